// Round 18
// baseline (85.549 us; speedup 1.0000x reference)
//
#include <hip/hip_runtime.h>

#define TT 200
#define FF 32
#define HH 50
#define NCH 13   // ceil(TT/16) chunks of 16 timesteps

typedef _Float16 half8 __attribute__((ext_vector_type(8)));   // 8 f16 = 4 VGPR
typedef __attribute__((ext_vector_type(4))) float f32x4;
typedef __attribute__((ext_vector_type(4))) unsigned int uint32x4;

// tanh(x) = 1 - 2/(exp2(2*log2e*x)+1)
__device__ __forceinline__ float fast_tanh(float x) {
    float e = exp2f(2.885390082f * x);
    return fmaf(-2.0f, __builtin_amdgcn_rcpf(e + 1.0f), 1.0f);
}
__device__ __forceinline__ f32x4 mfmah(half8 a, half8 b, f32x4 c) {
    return __builtin_amdgcn_mfma_f32_16x16x32_f16(a, b, c, 0, 0, 0);
}

// fp16 B-frag of M[kdim x 50] col-slice (RNE). Layout (validated r4-r17):
// lane(r,g) elem e -> B[k=kbase+8g+e][col=c].
__device__ __forceinline__ half8 build_wfrag(const float* __restrict__ M, int kbase,
                                             int kmax, int c, bool cv, int g) {
    unsigned u[4];
#pragma unroll
    for (int q = 0; q < 4; ++q) {
        const int k0 = kbase + 8 * g + 2 * q, k1 = k0 + 1;
        _Float16 v0 = (_Float16)((cv && k0 < kmax) ? M[k0 * HH + c] : 0.0f);
        _Float16 v1 = (_Float16)((cv && k1 < kmax) ? M[k1 * HH + c] : 0.0f);
        u[q] = ((unsigned)__builtin_bit_cast(unsigned short, v1) << 16)
             |  __builtin_bit_cast(unsigned short, v0);
    }
    uint32x4 uu = {u[0], u[1], u[2], u[3]};
    return __builtin_bit_cast(half8, uu);
}

// 8 f32 -> half8 via v_cvt_pkrtz (x-GEMM A path)
__device__ __forceinline__ half8 cvt8(float4 a, float4 b) {
    unsigned u0 = __builtin_bit_cast(unsigned, __builtin_amdgcn_cvt_pkrtz(a.x, a.y));
    unsigned u1 = __builtin_bit_cast(unsigned, __builtin_amdgcn_cvt_pkrtz(a.z, a.w));
    unsigned u2 = __builtin_bit_cast(unsigned, __builtin_amdgcn_cvt_pkrtz(b.x, b.y));
    unsigned u3 = __builtin_bit_cast(unsigned, __builtin_amdgcn_cvt_pkrtz(b.z, b.w));
    uint32x4 uu = {u0, u1, u2, u3};
    return __builtin_bit_cast(half8, uu);
}

// ONE WAVE per block, 4 REAL rows (M-dup x4), 1024 blocks (4 blocks/CU,
// 1 wave/SIMD). r17 post-mortem: VALUBusy includes MFMA issue -> pure VALU
// was already ~23 instr/step; the budget is LDS pipe (CU-shared, ~60%) and
// MFMA, both scaling with ROW-GROUP COUNT. dup x4 halves both per row vs
// dup x8, and has the magic property C-elem i == real row i for EVERY lane
// (4g+i mod 4 = i): all 4 accumulator elems are real, only a tile-select
// remains. h packed as u32 row-pairs (r15-validated pkrtz+perm, 2-way banks
// everywhere). Chunk x-GEMM + 16-step-ahead loads are independent in-wave
// work filling the h-path stalls that killed r15. Barrier/waitcnt-free.
__global__
__attribute__((amdgpu_flat_work_group_size(64, 64)))
__attribute__((amdgpu_waves_per_eu(1, 1)))
void rnn_fp16(const float* __restrict__ x, const float* __restrict__ W,
              const float* __restrict__ U, const float* __restrict__ b,
              const float* __restrict__ Wd, const float* __restrict__ bd,
              float* __restrict__ out)
{
    __shared__ float xw[2][16][4][64];    // [par][t'][row][col] 32 KB
    __shared__ unsigned hl[2][2][64];     // [buf][rowpair][col] packed f16x2

    const int l  = threadIdx.x & 63;
    const int r  = l & 15;
    const int g  = l >> 4;
    const int rp = (r & 3) >> 1;          // rowpair of this M-row's real row
    const int rb = blockIdx.x * 4;
    const bool gs1 = (g & 1) != 0, gs2 = (g & 2) != 0;
    const int cg = l;                     // this lane's owned h column (=16g+r)
    const unsigned psel = (r & 1) ? 0x07060302u : 0x05040100u;   // hi16 : lo16

    half8 Wf[4], U0[4], U1[4];
    f32x4 biasv[4];
#pragma unroll
    for (int n = 0; n < 4; ++n) {
        const int c = 16 * n + r;
        const bool cv = (c < HH);
        Wf[n] = build_wfrag(W, 0,  FF, c, cv, g);
        U0[n] = build_wfrag(U, 0,  HH, c, cv, g);
        U1[n] = build_wfrag(U, 32, HH, c, cv, g);
        const float bv = cv ? b[c] : 0.0f;
        biasv[n] = (f32x4){bv, bv, bv, bv};
    }
    const f32x4 kzero = {0.0f, 0.0f, 0.0f, 0.0f};
    const float wd = (cg < HH) ? Wd[cg] : 0.0f;

    const float* xr0 = x + (size_t)(rb + 0) * TT * FF;
    const float* xr1 = x + (size_t)(rb + 1) * TT * FF;
    const float* xr2 = x + (size_t)(rb + 2) * TT * FF;
    const float* xr3 = x + (size_t)(rb + 3) * TT * FF;

    // chunk staging registers (held 16 steps between load and compute)
    float4 s0a, s0b, s1a, s1b, s2a, s2b, s3a, s3b;
    auto chunk_load = [&](int cc) {
        int tt = 16 * cc + r; if (tt > TT - 1) tt = TT - 1;   // clamp tail
        const float* p0 = xr0 + (size_t)tt * FF + 8 * g;
        const float* p1 = xr1 + (size_t)tt * FF + 8 * g;
        const float* p2 = xr2 + (size_t)tt * FF + 8 * g;
        const float* p3 = xr3 + (size_t)tt * FF + 8 * g;
        s0a = *(const float4*)p0; s0b = *(const float4*)(p0 + 4);
        s1a = *(const float4*)p1; s1b = *(const float4*)(p1 + 4);
        s2a = *(const float4*)p2; s2b = *(const float4*)(p2 + 4);
        s3a = *(const float4*)p3; s3b = *(const float4*)(p3 + 4);
    };
    // xw[t'] = bias + x_t @ W for 16 timesteps x 4 rows (A rows = timesteps)
    auto chunk_compute = [&](int cc) {
        half8 a0 = cvt8(s0a, s0b), a1 = cvt8(s1a, s1b);
        half8 a2 = cvt8(s2a, s2b), a3 = cvt8(s3a, s3b);
        const int par = cc & 1;
#pragma unroll
        for (int n = 0; n < 4; ++n) {
            f32x4 c0 = mfmah(a0, Wf[n], biasv[n]);
            f32x4 c1 = mfmah(a1, Wf[n], biasv[n]);
            f32x4 c2 = mfmah(a2, Wf[n], biasv[n]);
            f32x4 c3 = mfmah(a3, Wf[n], biasv[n]);
#pragma unroll
            for (int i = 0; i < 4; ++i) {
                float* q = &xw[par][4 * g + i][0][16 * n + r];
                q[0]   = c0[i];
                q[64]  = c1[i];
                q[128] = c2[i];
                q[192] = c3[i];
            }
        }
    };

    // prologue: chunk 0 computed; chunk 1 loads in flight; h buf0 = 0
    chunk_load(0);
    chunk_compute(0);
    chunk_load(1);
    hl[0][0][l] = 0u;
    hl[0][1][l] = 0u;

    float h0 = 0.0f, h1 = 0.0f, h2 = 0.0f, h3 = 0.0f;

    for (int c = 0; c < NCH; ++c) {
        const int par = c & 1;
        const int nsteps = (c == NCH - 1) ? (TT - 16 * (NCH - 1)) : 16;
#pragma unroll
        for (int tl = 0; tl < 16; ++tl) {
            if (tl >= nsteps) break;
            const int buf = tl & 1;
            // h_t A-frags: 4 b128 (2-way banks, broadcast) + 8 perms
            const unsigned* hp = &hl[buf][rp][0];
            uint32x4 w0 = *(const uint32x4*)(hp + 8 * g);
            uint32x4 w1 = *(const uint32x4*)(hp + 8 * g + 4);
            uint32x4 w2 = *(const uint32x4*)(hp + 32 + 8 * g);
            uint32x4 w3 = *(const uint32x4*)(hp + 32 + 8 * g + 4);
            uint32x4 pa = {__builtin_amdgcn_perm(w0[1], w0[0], psel),
                           __builtin_amdgcn_perm(w0[3], w0[2], psel),
                           __builtin_amdgcn_perm(w1[1], w1[0], psel),
                           __builtin_amdgcn_perm(w1[3], w1[2], psel)};
            uint32x4 pb = {__builtin_amdgcn_perm(w2[1], w2[0], psel),
                           __builtin_amdgcn_perm(w2[3], w2[2], psel),
                           __builtin_amdgcn_perm(w3[1], w3[0], psel),
                           __builtin_amdgcn_perm(w3[3], w3[2], psel)};
            half8 A0 = __builtin_bit_cast(half8, pa);
            half8 A1 = __builtin_bit_cast(half8, pb);

            f32x4 tot[4];
#pragma unroll
            for (int n = 0; n < 4; ++n)   // serial 2-chain, persistent zero C
                tot[n] = mfmah(A1, U1[n], mfmah(A0, U0[n], kzero));

            // mid-chunk: next chunk's xw GEMM + loads for the one after
            if (tl == 8) {
                if (c + 1 < NCH) chunk_compute(c + 1);
                if (c + 2 < NCH) chunk_load(c + 2);
            }

            // tile-select (lane owns col cg = tile g); elem i == real row i
            float m0 = gs2 ? (gs1 ? tot[3][0] : tot[2][0]) : (gs1 ? tot[1][0] : tot[0][0]);
            float m1 = gs2 ? (gs1 ? tot[3][1] : tot[2][1]) : (gs1 ? tot[1][1] : tot[0][1]);
            float m2 = gs2 ? (gs1 ? tot[3][2] : tot[2][2]) : (gs1 ? tot[1][2] : tot[0][2]);
            float m3 = gs2 ? (gs1 ? tot[3][3] : tot[2][3]) : (gs1 ? tot[1][3] : tot[0][3]);

            const float* xq = &xw[par][tl][0][cg];   // 4 b32, stride-64, 2-way
            m0 += xq[0];
            m1 += xq[64];
            m2 += xq[128];
            m3 += xq[192];
            h0 = fast_tanh(m0);
            h1 = fast_tanh(m1);
            h2 = fast_tanh(m2);
            h3 = fast_tanh(m3);
            // publish: 2 packed u32 writes (2-way banks, free)
            hl[buf ^ 1][0][cg] = __builtin_bit_cast(unsigned,
                __builtin_amdgcn_cvt_pkrtz(h0, h1));
            hl[buf ^ 1][1][cg] = __builtin_bit_cast(unsigned,
                __builtin_amdgcn_cvt_pkrtz(h2, h3));
            // no barrier, no waitcnt: wave-private in-order DS
        }
    }

    // head: out[row i] = relu(sum_c h[i][c]*Wd[c] + bd)
    float p0 = h0 * wd, p1 = h1 * wd, p2 = h2 * wd, p3 = h3 * wd;
#pragma unroll
    for (int m = 1; m <= 32; m <<= 1) {
        p0 += __shfl_xor(p0, m);
        p1 += __shfl_xor(p1, m);
        p2 += __shfl_xor(p2, m);
        p3 += __shfl_xor(p3, m);
    }
    if (l == 0) {
        const float bdv = bd[0];
        out[rb + 0] = fmaxf(p0 + bdv, 0.0f);
        out[rb + 1] = fmaxf(p1 + bdv, 0.0f);
        out[rb + 2] = fmaxf(p2 + bdv, 0.0f);
        out[rb + 3] = fmaxf(p3 + bdv, 0.0f);
    }
}

extern "C" void kernel_launch(void* const* d_in, const int* in_sizes, int n_in,
                              void* d_out, int out_size, void* d_ws, size_t ws_size,
                              hipStream_t stream) {
    const float* x  = (const float*)d_in[0];
    const float* W  = (const float*)d_in[1];
    const float* U  = (const float*)d_in[2];
    const float* b  = (const float*)d_in[3];
    const float* Wd = (const float*)d_in[4];
    const float* bd = (const float*)d_in[5];
    float* out = (float*)d_out;
    const int B = out_size;                       // 4096
    dim3 grid(B / 4), block(64);                  // 1024 blocks, 1 wave, 4 rows
    hipLaunchKernelGGL(rnn_fp16, grid, block, 0, stream,
                       x, W, U, b, Wd, bd, out);
    (void)d_ws; (void)ws_size; (void)in_sizes; (void)n_in;
}

// Round 19
// 76.532 us; speedup vs baseline: 1.1178x; 1.1178x over previous
//
#include <hip/hip_runtime.h>

#define TT 200
#define FF 32
#define HH 50

typedef _Float16 half8 __attribute__((ext_vector_type(8)));   // 8 f16 = 4 VGPR
typedef __attribute__((ext_vector_type(4))) float f32x4;
typedef __attribute__((ext_vector_type(4))) unsigned int uint32x4;

// tanh(x) = 1 - 2/(exp2(2*log2e*x)+1)
__device__ __forceinline__ float fast_tanh(float x) {
    float e = exp2f(2.885390082f * x);
    return fmaf(-2.0f, __builtin_amdgcn_rcpf(e + 1.0f), 1.0f);
}
__device__ __forceinline__ f32x4 mfmah(half8 a, half8 b, f32x4 c) {
    return __builtin_amdgcn_mfma_f32_16x16x32_f16(a, b, c, 0, 0, 0);
}

// fp16 B-frag of M[kdim x 50] col-slice (RNE). Layout (validated r4-r18):
// lane(r,g) elem e -> B[k=kbase+8g+e][col=c].
__device__ __forceinline__ half8 build_wfrag(const float* __restrict__ M, int kbase,
                                             int kmax, int c, bool cv, int g) {
    unsigned u[4];
#pragma unroll
    for (int q = 0; q < 4; ++q) {
        const int k0 = kbase + 8 * g + 2 * q, k1 = k0 + 1;
        _Float16 v0 = (_Float16)((cv && k0 < kmax) ? M[k0 * HH + c] : 0.0f);
        _Float16 v1 = (_Float16)((cv && k1 < kmax) ? M[k1 * HH + c] : 0.0f);
        u[q] = ((unsigned)__builtin_bit_cast(unsigned short, v1) << 16)
             |  __builtin_bit_cast(unsigned short, v0);
    }
    uint32x4 uu = {u[0], u[1], u[2], u[3]};
    return __builtin_bit_cast(half8, uu);
}

// 8 f32 -> half8 via v_cvt_pkrtz
__device__ __forceinline__ half8 cvt8(float4 a, float4 b) {
    unsigned u0 = __builtin_bit_cast(unsigned, __builtin_amdgcn_cvt_pkrtz(a.x, a.y));
    unsigned u1 = __builtin_bit_cast(unsigned, __builtin_amdgcn_cvt_pkrtz(a.z, a.w));
    unsigned u2 = __builtin_bit_cast(unsigned, __builtin_amdgcn_cvt_pkrtz(b.x, b.y));
    unsigned u3 = __builtin_bit_cast(unsigned, __builtin_amdgcn_cvt_pkrtz(b.z, b.w));
    uint32x4 uu = {u0, u1, u2, u3};
    return __builtin_bit_cast(half8, uu);
}

// r16 shell (1 wave/block, 2 real rows M-dup x8, 2048 blocks = 2 waves/SIMD,
// barrier/waitcnt-free wave-private h) with the xw LDS staging DELETED
// (r18 post-mortem: LDS pipe is the top CU consumer at ~464 cyc/step; xw
// staging was ~24 of each wave's ~58 DS-cyc + 16 KB + chunk machinery):
// x@W is fused into the h-MFMA chain as its C-root —
//   tot[n] = A1*U1 + (A0*U0 + (xa*Wf + bias))
// with xa loaded straight from global per step (8-lane-duplicated rows ->
// L1/L3 broadcast; x is L3-resident) and cvt'd in 4 pkrtz. The x-MFMA is
// h-independent, so it issues under the h-read latency; path from h-ready
// is still 2 MFMAs. LDS is now h-only: 2 b128 + 2 b16 per step (512 B).
__global__
__attribute__((amdgpu_flat_work_group_size(64, 64)))
__attribute__((amdgpu_waves_per_eu(2, 2)))
void rnn_fp16(const float* __restrict__ x, const float* __restrict__ W,
              const float* __restrict__ U, const float* __restrict__ b,
              const float* __restrict__ Wd, const float* __restrict__ bd,
              float* __restrict__ out)
{
    __shared__ _Float16 hl[2][2][64];     // [buf][row][col] 512 B

    const int l  = threadIdx.x & 63;
    const int r  = l & 15;
    const int g  = l >> 4;
    const int rl = r & 1;                 // real row (M-dup x8)
    const int rb = blockIdx.x * 2;
    const bool gs1 = (g & 1) != 0, gs2 = (g & 2) != 0;
    const int cg = l;                     // this lane's owned h column (=16g+r)

    // weight frags (48 VGPR) + persistent bias C-source (16 VGPR)
    half8 Wf[4], U0[4], U1[4];
    f32x4 biasv[4];
#pragma unroll
    for (int n = 0; n < 4; ++n) {
        const int c = 16 * n + r;
        const bool cv = (c < HH);
        Wf[n] = build_wfrag(W, 0,  FF, c, cv, g);
        U0[n] = build_wfrag(U, 0,  HH, c, cv, g);
        U1[n] = build_wfrag(U, 32, HH, c, cv, g);
        const float bv = cv ? b[c] : 0.0f;
        biasv[n] = (f32x4){bv, bv, bv, bv};
    }
    const float wd = (cg < HH) ? Wd[cg] : 0.0f;

    // x stream: lane holds x[rb+rl][t][8g..8g+7]; prefetch depth 2
    const float* xrow = x + (size_t)(rb + rl) * TT * FF + 8 * g;
    float4 pa0 = *(const float4*)(xrow),          pa1 = *(const float4*)(xrow + 4);
    float4 pb0 = *(const float4*)(xrow + FF),     pb1 = *(const float4*)(xrow + FF + 4);

    // h buf0 = 0 (cols >= 50 stay 0 forever: zero weight frags -> tanh(0))
    hl[0][0][cg] = (_Float16)0.0f;
    hl[0][1][cg] = (_Float16)0.0f;

    float h0f = 0.0f, h1f = 0.0f;

    auto step = [&](int t, bool first, float4& qa, float4& qb) {
        const int buf = t & 1;
        // h_t A-frags first (deepest latency; in-order wave-private DS)
        half8 A0, A1;
        if (!first) {
            A0 = *(const half8*)(&hl[buf][rl][8 * g]);        // k 0..31
            A1 = *(const half8*)(&hl[buf][rl][32 + 8 * g]);   // k 32..63 (pad 0)
        }
        // x_t A-frag (loaded 2 steps ago) + advance prefetch to t+2
        half8 xa = cvt8(qa, qb);
        int tn = t + 2; if (tn > TT - 1) tn = TT - 1;
        qa = *(const float4*)(xrow + (size_t)tn * FF);
        qb = *(const float4*)(xrow + (size_t)tn * FF + 4);

        f32x4 tot[4];
#pragma unroll
        for (int n = 0; n < 4; ++n) {
            // x-MFMA is the C-root (h-independent, issues under h-read)
            f32x4 c = mfmah(xa, Wf[n], biasv[n]);
            if (!first)
                c = mfmah(A1, U1[n], mfmah(A0, U0[n], c));
            tot[n] = c;
        }

        // select tile g (lane owns col cg); elems 0,1 = real rows 0,1
        float m0 = gs2 ? (gs1 ? tot[3][0] : tot[2][0]) : (gs1 ? tot[1][0] : tot[0][0]);
        float m1 = gs2 ? (gs1 ? tot[3][1] : tot[2][1]) : (gs1 ? tot[1][1] : tot[0][1]);
        h0f = fast_tanh(m0);
        h1f = fast_tanh(m1);
        hl[buf ^ 1][0][cg] = (_Float16)h0f;   // 2-way write banks: free
        hl[buf ^ 1][1][cg] = (_Float16)h1f;
        // no barrier, no waitcnt: wave-private in-order DS
    };

    step(0, true, pa0, pa1);
    for (int t = 1; t < TT - 1; t += 2) {
        step(t,     false, pb0, pb1);
        step(t + 1, false, pa0, pa1);
    }
    step(TT - 1, false, pb0, pb1);          // t=199 odd -> pb

    // head: out[row i] = relu(sum_c h[i][c]*Wd[c] + bd)
    float p0 = h0f * wd, p1 = h1f * wd;
#pragma unroll
    for (int m = 1; m <= 32; m <<= 1) {
        p0 += __shfl_xor(p0, m);
        p1 += __shfl_xor(p1, m);
    }
    if (l == 0) {
        const float bdv = bd[0];
        out[rb + 0] = fmaxf(p0 + bdv, 0.0f);
        out[rb + 1] = fmaxf(p1 + bdv, 0.0f);
    }
}

extern "C" void kernel_launch(void* const* d_in, const int* in_sizes, int n_in,
                              void* d_out, int out_size, void* d_ws, size_t ws_size,
                              hipStream_t stream) {
    const float* x  = (const float*)d_in[0];
    const float* W  = (const float*)d_in[1];
    const float* U  = (const float*)d_in[2];
    const float* b  = (const float*)d_in[3];
    const float* Wd = (const float*)d_in[4];
    const float* bd = (const float*)d_in[5];
    float* out = (float*)d_out;
    const int B = out_size;                       // 4096
    dim3 grid(B / 2), block(64);                  // 2048 blocks, 1 wave, 2 rows
    hipLaunchKernelGGL(rnn_fp16, grid, block, 0, stream,
                       x, W, U, b, Wd, bd, out);
    (void)d_ws; (void)ws_size; (void)in_sizes; (void)n_in;
}

// Round 20
// 61.408 us; speedup vs baseline: 1.3931x; 1.2463x over previous
//
#include <hip/hip_runtime.h>

#define TT 200
#define FF 32
#define HH 50
#define NFULL 12   // 12 full 16-step chunks + 8-step tail (chunk 12)

typedef _Float16 half8 __attribute__((ext_vector_type(8)));   // 8 f16 = 4 VGPR
typedef __attribute__((ext_vector_type(4))) float f32x4;
typedef __attribute__((ext_vector_type(4))) unsigned int uint32x4;

// tanh(x) = 1 - 2/(exp2(2*log2e*x)+1)
__device__ __forceinline__ float fast_tanh(float x) {
    float e = exp2f(2.885390082f * x);
    return fmaf(-2.0f, __builtin_amdgcn_rcpf(e + 1.0f), 1.0f);
}
__device__ __forceinline__ f32x4 mfmah(half8 a, half8 b, f32x4 c) {
    return __builtin_amdgcn_mfma_f32_16x16x32_f16(a, b, c, 0, 0, 0);
}

// fp16 B-frag of M[kdim x 50] col-slice (RNE). Layout (validated r4-r19):
// lane(r,g) elem e -> B[k=kbase+8g+e][col=c].
__device__ __forceinline__ half8 build_wfrag(const float* __restrict__ M, int kbase,
                                             int kmax, int c, bool cv, int g) {
    unsigned u[4];
#pragma unroll
    for (int q = 0; q < 4; ++q) {
        const int k0 = kbase + 8 * g + 2 * q, k1 = k0 + 1;
        _Float16 v0 = (_Float16)((cv && k0 < kmax) ? M[k0 * HH + c] : 0.0f);
        _Float16 v1 = (_Float16)((cv && k1 < kmax) ? M[k1 * HH + c] : 0.0f);
        u[q] = ((unsigned)__builtin_bit_cast(unsigned short, v1) << 16)
             |  __builtin_bit_cast(unsigned short, v0);
    }
    uint32x4 uu = {u[0], u[1], u[2], u[3]};
    return __builtin_bit_cast(half8, uu);
}

// 8 f32 -> half8 via v_cvt_pkrtz (x-GEMM A path)
__device__ __forceinline__ half8 cvt8(float4 a, float4 b) {
    unsigned u0 = __builtin_bit_cast(unsigned, __builtin_amdgcn_cvt_pkrtz(a.x, a.y));
    unsigned u1 = __builtin_bit_cast(unsigned, __builtin_amdgcn_cvt_pkrtz(a.z, a.w));
    unsigned u2 = __builtin_bit_cast(unsigned, __builtin_amdgcn_cvt_pkrtz(b.x, b.y));
    unsigned u3 = __builtin_bit_cast(unsigned, __builtin_amdgcn_cvt_pkrtz(b.z, b.w));
    uint32x4 uu = {u0, u1, u2, u3};
    return __builtin_bit_cast(half8, uu);
}

// Champion r16 shell (1 wave/block, 2 real rows M-dup x8, 2048 blocks =
// 2 phase-independent waves/SIMD, chunk-batched x-GEMM staged in LDS f32,
// f16 h in LDS, barrier/waitcnt-free wave-private recurrence) with the
// unroll done RIGHT (r17's break-inside-unroll kept the trip runtime, so
// nothing changed): 12 full chunks with an unconditional fully-unrolled
// 16-step body (tl/buf compile-time -> immediate LDS offsets, no per-step
// branches; chunk_load's internal clamp makes the c+2 prefetch safe even
// for the nonexistent chunk 13) + a separate branchless 8-step tail.
__global__
__attribute__((amdgpu_flat_work_group_size(64, 64)))
__attribute__((amdgpu_waves_per_eu(2, 2)))
void rnn_fp16(const float* __restrict__ x, const float* __restrict__ W,
              const float* __restrict__ U, const float* __restrict__ b,
              const float* __restrict__ Wd, const float* __restrict__ bd,
              float* __restrict__ out)
{
    __shared__ float xw[2][16][2][64];    // [chunk parity][t&15][row][col] 16 KB
    __shared__ _Float16 hl[2][2][64];     // [buf][row][col] 512 B

    const int l = threadIdx.x & 63;
    const int r = l & 15;
    const int g = l >> 4;
    const int rl = r & 1;                 // real row (M-dup x8)
    const int rb = blockIdx.x * 2;
    const bool gs1 = (g & 1) != 0, gs2 = (g & 2) != 0;
    const int cg = 16 * g + r;            // this lane's h column (0..63)

    half8 Wf[4], U0[4], U1[4];
    f32x4 biasv[4];
#pragma unroll
    for (int n = 0; n < 4; ++n) {
        const int c = 16 * n + r;
        const bool cv = (c < HH);
        Wf[n] = build_wfrag(W, 0,  FF, c, cv, g);
        U0[n] = build_wfrag(U, 0,  HH, c, cv, g);
        U1[n] = build_wfrag(U, 32, HH, c, cv, g);
        const float bv = cv ? b[c] : 0.0f;
        biasv[n] = (f32x4){bv, bv, bv, bv};
    }
    const f32x4 kzero = {0.0f, 0.0f, 0.0f, 0.0f};
    const float wd = (cg < HH) ? Wd[cg] : 0.0f;

    const float* x0 = x + (size_t)(rb + 0) * TT * FF;
    const float* x1 = x + (size_t)(rb + 1) * TT * FF;

    // chunk staging registers (held 16 steps between load and compute)
    float4 r0a, r0b, r1a, r1b;
    auto chunk_load = [&](int cc) {
        int tt = 16 * cc + r; if (tt > TT - 1) tt = TT - 1;   // clamp: safe for cc>12
        const float* p0 = x0 + (size_t)tt * FF + 8 * g;
        const float* p1 = x1 + (size_t)tt * FF + 8 * g;
        r0a = *(const float4*)p0; r0b = *(const float4*)(p0 + 4);
        r1a = *(const float4*)p1; r1b = *(const float4*)(p1 + 4);
    };
    // xw[t] = bias + x_t @ W for 16 timesteps (M = timesteps GEMM) -> LDS f32
    auto chunk_compute = [&](int cc) {
        half8 a0 = cvt8(r0a, r0b);
        half8 a1 = cvt8(r1a, r1b);
        const int par = cc & 1;
#pragma unroll
        for (int n = 0; n < 4; ++n) {
            f32x4 c0 = mfmah(a0, Wf[n], biasv[n]);
            f32x4 c1 = mfmah(a1, Wf[n], biasv[n]);
#pragma unroll
            for (int i = 0; i < 4; ++i) {
                xw[par][4 * g + i][0][16 * n + r] = c0[i];
                xw[par][4 * g + i][1][16 * n + r] = c1[i];
            }
        }
    };

    // prologue: chunk 0 computed; chunk 1 loads in flight; h buf0 = 0
    chunk_load(0);
    chunk_compute(0);
    chunk_load(1);
    ((unsigned*)hl)[l] = 0u;              // zero both h buffers (512 B)
    ((unsigned*)hl)[64 + l] = 0u;

    float hf0 = 0.0f, hf1 = 0.0f;

    // one step, tl compile-time: immediate LDS offsets, branchless
    auto step_body = [&](int tl, const float* xwp, bool first) {
        const int buf = tl & 1;
        half8 A0, A1;
        if (!first) {
            const _Float16* hp = &hl[buf][rl][0];
            A0 = *(const half8*)(hp + 8 * g);            // k 0..31
            A1 = *(const half8*)(hp + 32 + 8 * g);       // k 32..63 (pad 0)
        }
        f32x4 tot[4];
        if (!first) {
#pragma unroll
            for (int n = 0; n < 4; ++n)   // serial 2-chain, persistent zero C
                tot[n] = mfmah(A1, U1[n], mfmah(A0, U0[n], kzero));
        } else {
#pragma unroll
            for (int n = 0; n < 4; ++n) tot[n] = kzero;
        }
        // select tile g, add xw (immediate-offset b32 reads), tanh, publish
        float m0 = gs2 ? (gs1 ? tot[3][0] : tot[2][0]) : (gs1 ? tot[1][0] : tot[0][0]);
        float m1 = gs2 ? (gs1 ? tot[3][1] : tot[2][1]) : (gs1 ? tot[1][1] : tot[0][1]);
        m0 += xwp[tl * 128];              // xw[par][tl][0][cg]
        m1 += xwp[tl * 128 + 64];         // xw[par][tl][1][cg]
        hf0 = fast_tanh(m0);
        hf1 = fast_tanh(m1);
        hl[buf ^ 1][0][cg] = (_Float16)hf0;   // 2-way banks: free
        hl[buf ^ 1][1][cg] = (_Float16)hf1;
        // no barrier, no waitcnt: wave-private in-order DS
    };

    // 12 full chunks, 16 steps each, fully unrolled and branchless
    for (int c = 0; c < NFULL; ++c) {
        const float* xwp = (c & 1) ? &xw[1][0][0][cg] : &xw[0][0][0][cg];
#pragma unroll
        for (int tl = 0; tl < 16; ++tl) {
            step_body(tl, xwp, (c == 0) & (tl == 0));
            if (tl == 8) {                // compile-time position, no branch
                chunk_compute(c + 1);     // c+1 <= 12: always valid
                chunk_load(c + 2);        // c+2 == 13 clamps harmlessly
            }
        }
    }
    // tail: chunk 12 (parity 0), steps t = 192..199, no prefetch machinery
    {
        const float* xwp = &xw[0][0][0][cg];
#pragma unroll
        for (int tl = 0; tl < 8; ++tl) step_body(tl, xwp, false);
    }

    // head: out[row i] = relu(sum_c h[i][c]*Wd[c] + bd)
    float p0 = hf0 * wd, p1 = hf1 * wd;
#pragma unroll
    for (int m = 1; m <= 32; m <<= 1) {
        p0 += __shfl_xor(p0, m);
        p1 += __shfl_xor(p1, m);
    }
    if (l == 0) {
        const float bdv = bd[0];
        out[rb + 0] = fmaxf(p0 + bdv, 0.0f);
        out[rb + 1] = fmaxf(p1 + bdv, 0.0f);
    }
}

extern "C" void kernel_launch(void* const* d_in, const int* in_sizes, int n_in,
                              void* d_out, int out_size, void* d_ws, size_t ws_size,
                              hipStream_t stream) {
    const float* x  = (const float*)d_in[0];
    const float* W  = (const float*)d_in[1];
    const float* U  = (const float*)d_in[2];
    const float* b  = (const float*)d_in[3];
    const float* Wd = (const float*)d_in[4];
    const float* bd = (const float*)d_in[5];
    float* out = (float*)d_out;
    const int B = out_size;                       // 4096
    dim3 grid(B / 2), block(64);                  // 2048 blocks, 1 wave, 2 rows
    hipLaunchKernelGGL(rnn_fp16, grid, block, 0, stream,
                       x, W, U, b, Wd, bd, out);
    (void)d_ws; (void)ws_size; (void)in_sizes; (void)n_in;
}